// Round 18
// baseline (65.759 us; speedup 1.0000x reference)
//
#include <hip/hip_runtime.h>
#include <hip/hip_bf16.h>

// GMM log-likelihood, N=65536, K=32, F=128.
// R17 structure (triangular compaction, s >= 2q -> 20 chunks/comp; wave
// (p,nq): p=0 owns g-tiles {0,3}, p=1 owns {1,2}; 10 frags -> 20 MFMAs/comp;
// pairwise xch combine; v-trick; 1 barrier/comp) with two work cuts:
// 1) squares via v_pk_fma_f32 (packed dual FMA, 4 indep chains) -- halves
//    the 1024 cyc/comp/CU VALU square cost;
// 2) ALL preps fused into one kernel (block k: mu-projection -> v -> Ximg
//    direct scalar writes -> ck3 -> triangular slab build) -- 2 launches
//    total instead of 5.

#define NPTS 65536
#define KC 32
#define FD 128
#define SLABB 20480  // 20 chunks * 64 lanes * 16 B per component (triangular)

typedef __attribute__((ext_vector_type(8))) short short8;
typedef __attribute__((ext_vector_type(8))) unsigned short ushort8;
typedef __attribute__((ext_vector_type(16))) float f32x16;
typedef __attribute__((ext_vector_type(2))) float f32x2;

#define MFMA(A, B, C) __builtin_amdgcn_mfma_f32_32x32x16_bf16((A), (B), (C), 0, 0, 0)

static __device__ __forceinline__ unsigned short f2bf(float f) {
  unsigned int u = __float_as_uint(f);
  u += 0x7FFFu + ((u >> 16) & 1u);  // RNE
  return (unsigned short)(u >> 16);
}

static __device__ __forceinline__ void gll(const unsigned char* g, unsigned char* l) {
  __builtin_amdgcn_global_load_lds((const __attribute__((address_space(1))) void*)g,
                                   (__attribute__((address_space(3))) void*)l, 16, 0, 0);
}

// packed square-accumulate: acc.lo += y.lo^2, acc.hi += y.hi^2
static __device__ __forceinline__ void pksq(f32x2& acc, float lo, float hi) {
  f32x2 y;
  y[0] = lo;
  y[1] = hi;
  asm("v_pk_fma_f32 %0, %1, %1, %0" : "+v"(acc) : "v"(y));
}

// --- prep_all: one block per component k (256 threads). ---
// t<128: mp[t] = mu_k @ P_k[:,t]; then v[t] = P_k[t,:] @ mp -> Ximg (scalar
// bf16 store at frag-major position row k, col t); reductions -> ck3.
// Then all 256 threads build the 20-chunk triangular slab of Aimg.
__global__ void prep_all(const float* __restrict__ means, const float* __restrict__ P,
                         const float* __restrict__ w, unsigned char* __restrict__ Aimg,
                         unsigned char* __restrict__ Ximg, float* __restrict__ ck3) {
  const int k = blockIdx.x;   // 0..31
  const int t = threadIdx.x;  // 0..255
  const float* Pk = P + k * FD * FD;
  __shared__ float smp[FD], r1[FD], r2[FD];
  if (t < FD) {
    float acc = 0.f;
    for (int f = 0; f < FD; ++f) acc = fmaf(means[k * FD + f], Pk[f * FD + t], acc);
    smp[t] = acc;
    r1[t] = logf(Pk[t * FD + t]);
    r2[t] = acc * acc;
  }
  __syncthreads();
  if (t < FD) {
    const float* Pr = Pk + t * FD;
    float a2 = 0.f;
    for (int j = 0; j < FD; ++j) a2 = fmaf(Pr[j], smp[j], a2);
    // Ximg frag-major position for (row k, col t):
    // chunk id = (t>>4)*64 + k + 32*((t>>3)&1); byte within chunk = (t&7)*2
    const int id = ((t >> 4) * 64) + k + 32 * ((t >> 3) & 1);
    *(unsigned short*)(Ximg + (size_t)id * 16 + (t & 7) * 2) = f2bf(a2);
  }
  for (int off = 64; off; off >>= 1) {
    if (t < off) { r1[t] += r1[t + off]; r2[t] += r2[t + off]; }
    __syncthreads();
  }
  if (t == 0)
    ck3[k] = logf(w[k]) + r1[0] - 0.5f * ((float)FD * 1.8378770664093453f + r2[0]);
  // triangular A image: 20 chunks c x 64 lanes l = 1280 stores, 5 per thread.
  // c<8: (q=0,s=c); c<10: (q=3,s=c-2); c<16: (q=1,s=c-8); else (q=2,s=c-12).
  for (int i = t; i < 1280; i += 256) {
    const int c = i >> 6, l = i & 63;
    int q, s;
    if (c < 8)       { q = 0; s = c; }
    else if (c < 10) { q = 3; s = c - 2; }
    else if (c < 16) { q = 1; s = c - 8; }
    else             { q = 2; s = c - 12; }
    const int g = q * 32 + (l & 31);
    const int f0 = 16 * s + 8 * (l >> 5);
    ushort8 o;
#pragma unroll
    for (int j = 0; j < 8; ++j) o[j] = f2bf(Pk[(f0 + j) * FD + g]);
    *(ushort8*)(Aimg + (size_t)k * SLABB + (size_t)i * 16) = o;
  }
}

// --- main ---
__global__ __launch_bounds__(256, 2) void gmm_main(const float* __restrict__ x,
                                                   const unsigned char* __restrict__ Aimg,
                                                   const unsigned char* __restrict__ Ximg,
                                                   const float* __restrict__ ck3,
                                                   float* __restrict__ out) {
  __shared__ __align__(16) unsigned char abuf[2 * SLABB];  // 40 KB
  __shared__ __align__(16) float xch[2][4][32];
  __shared__ float ck[KC];
  const int tid = threadIdx.x;
  const int wid = tid >> 6;
  const int lane = tid & 63;
  const int half = lane >> 5;
  const int ln = lane & 31;
  const int p = wid & 1;    // g-tile pair: p=0 -> {0,3}, p=1 -> {1,2}
  const int nq = wid >> 1;  // n-half this wave owns (64 x-rows, tiles t=0,1)
  const int nbase = blockIdx.x * 128;

  if (tid < KC) ck[tid] = ck3[tid];

  // prologue staging: Ximg (8 KB) -> buf1, slab0 -> buf0 (5 gll/wave)
  {
    const unsigned char* gx = Ximg + wid * 2048 + lane * 16;
    unsigned char* lx = abuf + SLABB + wid * 2048;
    gll(gx, lx);
    gll(gx + 1024, lx + 1024);
    const unsigned char* gs = Aimg + wid * 5120 + lane * 16;
    unsigned char* ls = abuf + wid * 5120;
#pragma unroll
    for (int i = 0; i < 5; ++i) gll(gs + i * 1024, ls + i * 1024);
  }

  // B fragments: this wave's 64 x-rows (2 n-tiles), resident all kernel.
  // xf[t][s][j] = x[nbase + nq*64 + t*32 + ln][16s + 8*half + j]  (64 VGPR)
  short8 xf[2][8];
#pragma unroll
  for (int t = 0; t < 2; ++t) {
    const float* xr = x + (size_t)(nbase + nq * 64 + t * 32 + ln) * FD + 8 * half;
#pragma unroll
    for (int s = 0; s < 8; ++s) {
      const float4 a = *(const float4*)(xr + 16 * s);
      const float4 b = *(const float4*)(xr + 16 * s + 4);
      short8 f;
      f[0] = (short)f2bf(a.x); f[1] = (short)f2bf(a.y);
      f[2] = (short)f2bf(a.z); f[3] = (short)f2bf(a.w);
      f[4] = (short)f2bf(b.x); f[5] = (short)f2bf(b.y);
      f[6] = (short)f2bf(b.z); f[7] = (short)f2bf(b.w);
      xf[t][s] = f;
    }
  }

  f32x16 zc;  // persistent zero C-operand
#pragma unroll
  for (int i = 0; i < 16; ++i) zc[i] = 0.f;

  asm volatile("s_waitcnt vmcnt(0)" ::: "memory");
  __syncthreads();

  // xv[n,k] mini-GEMM for the n-tile this wave finalizes (t == p):
  // row k = (i&3)+8*(i>>2)+4*half, col n = nbase + nq*64 + p*32 + ln
  // NOTE: ternary register-select, never xf[p][s] (rule-20).
  f32x16 xv;
  {
    const unsigned char* xb = abuf + SLABB + lane * 16;
    {
      const short8 fx = *(const short8*)xb;
      xv = MFMA(fx, p ? xf[1][0] : xf[0][0], zc);
    }
#pragma unroll
    for (int s = 1; s < 8; ++s) {
      const short8 fx = *(const short8*)(xb + s * 1024);
      xv = MFMA(fx, p ? xf[1][s] : xf[0][s], xv);
    }
  }
  __syncthreads();  // Ximg consumed; buf1 free for slab1 staging

  float m = -__builtin_inff(), ssum = 0.f;

  for (int k = 0; k < KC; ++k) {
    const int RB = (k & 1) * SLABB;
    const int WB = SLABB - RB;
    const int ph = k & 1;
    // this wave's 10 triangular frags (consecutive chunks, conflict-free)
    const unsigned char* rb = abuf + RB + p * 10240 + lane * 16;
    short8 fr[10];
#pragma unroll
    for (int i = 0; i < 10; ++i) fr[i] = *(const short8*)(rb + i * 1024);
    if (k + 1 < KC) {  // stage slab k+1 (5 gll per wave)
      const unsigned char* gs = Aimg + (size_t)(k + 1) * SLABB + wid * 5120 + lane * 16;
      unsigned char* ls = abuf + WB + wid * 5120;
#pragma unroll
      for (int i = 0; i < 5; ++i) gll(gs + i * 1024, ls + i * 1024);
    }
    f32x16 a00, a01, a10, a11;
    __builtin_amdgcn_s_setprio(1);
    if (p == 0) {
      // g-tile 0: full K (s=0..7); g-tile 3: s=6,7
      a00 = MFMA(fr[0], xf[0][0], zc);
      a01 = MFMA(fr[0], xf[1][0], zc);
#pragma unroll
      for (int s = 1; s < 8; ++s) {
        a00 = MFMA(fr[s], xf[0][s], a00);
        a01 = MFMA(fr[s], xf[1][s], a01);
      }
      a10 = MFMA(fr[8], xf[0][6], zc);
      a11 = MFMA(fr[8], xf[1][6], zc);
      a10 = MFMA(fr[9], xf[0][7], a10);
      a11 = MFMA(fr[9], xf[1][7], a11);
    } else {
      // g-tile 1: s=2..7; g-tile 2: s=4..7
      a00 = MFMA(fr[0], xf[0][2], zc);
      a01 = MFMA(fr[0], xf[1][2], zc);
#pragma unroll
      for (int s = 1; s < 6; ++s) {
        a00 = MFMA(fr[s], xf[0][s + 2], a00);
        a01 = MFMA(fr[s], xf[1][s + 2], a01);
      }
      a10 = MFMA(fr[6], xf[0][4], zc);
      a11 = MFMA(fr[6], xf[1][4], zc);
#pragma unroll
      for (int j = 1; j < 4; ++j) {
        a10 = MFMA(fr[6 + j], xf[0][4 + j], a10);
        a11 = MFMA(fr[6 + j], xf[1][4 + j], a11);
      }
    }
    __builtin_amdgcn_s_setprio(0);
    // epilogue: packed squares (4 independent chains, v_pk_fma_f32)
    f32x2 s0a, s0b, s1a, s1b;
    s0a[0] = 0.f; s0a[1] = 0.f; s0b[0] = 0.f; s0b[1] = 0.f;
    s1a[0] = 0.f; s1a[1] = 0.f; s1b[0] = 0.f; s1b[1] = 0.f;
#pragma unroll
    for (int i = 0; i < 8; ++i) {
      pksq(s0a, a00[2 * i], a00[2 * i + 1]);
      pksq(s0b, a10[2 * i], a10[2 * i + 1]);
      pksq(s1a, a01[2 * i], a01[2 * i + 1]);
      pksq(s1b, a11[2 * i], a11[2 * i + 1]);
    }
    float q0 = (s0a[0] + s0a[1]) + (s0b[0] + s0b[1]);
    float q1 = (s1a[0] + s1a[1]) + (s1b[0] + s1b[1]);
    q0 += __shfl_xor(q0, 32, 64);  // both halves hold the 64-g pair partials
    q1 += __shfl_xor(q1, 32, 64);
    float sown = p ? q1 : q0;  // n-tile this wave finalizes (t == p)
    float soth = p ? q0 : q1;  // n-tile the partner (wid^1) finalizes
    if (half == 0) xch[ph][wid ^ 1][ln] = soth;
    if (k + 1 < KC) asm volatile("s_waitcnt vmcnt(0)" ::: "memory");
    __syncthreads();  // xch visibility + staging handoff (one barrier/comp)
    float sfull = sown + xch[ph][wid][ln];  // + partner's 64 g -> full 128-g
    // -2 * x.v_k, made half-uniform with one shfl
    const int owner = (k >> 2) & 1;
    const int idx = (k & 3) | ((k >> 3) << 2);
    float tx = (half == owner) ? xv[idx] : 0.f;
    tx += __shfl_xor(tx, 32, 64);
    sfull = fmaf(-2.f, tx, sfull);
    float vv = ck[k] - 0.5f * sfull;
    float nm = fmaxf(m, vv);
    ssum = ssum * __expf(m - nm) + __expf(vv - nm);
    m = nm;
  }

  if (half == 0) out[nbase + nq * 64 + p * 32 + ln] = m + logf(ssum);
}

extern "C" void kernel_launch(void* const* d_in, const int* in_sizes, int n_in,
                              void* d_out, int out_size, void* d_ws, size_t ws_size,
                              hipStream_t stream) {
  const float* x = (const float*)d_in[0];
  const float* means = (const float*)d_in[1];
  const float* P = (const float*)d_in[2];
  const float* w = (const float*)d_in[3];
  float* out = (float*)d_out;

  unsigned char* ws = (unsigned char*)d_ws;
  unsigned char* Aimg = ws;                      // 32 * 20480 = 655360 B
  unsigned char* Ximg = ws + 655360;             // 8192 B
  float* ck3 = (float*)(ws + 655360 + 8192);     // 128 B

  prep_all<<<32, 256, 0, stream>>>(means, P, w, Aimg, Ximg, ck3);
  gmm_main<<<NPTS / 128, 256, 0, stream>>>(x, Aimg, Ximg, ck3, out);
}

// Round 19
// 60.240 us; speedup vs baseline: 1.0916x; 1.0916x over previous
//
#include <hip/hip_runtime.h>
#include <hip/hip_bf16.h>

// GMM log-likelihood, N=65536, K=32, F=128.
// R17 main (triangular compaction, scalar-fmaf squares) + R18 fused prep.
// Wave (p,nq): p=0 owns g-tiles {0,3} (8+2 frags), p=1 owns {1,2} (6+4);
// 10 frags -> 20 MFMAs/comp; pairwise xch combine; v-trick; 1 barrier/comp.
// R18 lesson: v_pk_fma_f32 on AGPR-resident accumulators costs MORE than
// scalar fmaf (operand-pair assembly moves) -- scalar squares restored,
// ordered group1-then-group2 so group-1 squares hide group-2 MFMA drain.

#define NPTS 65536
#define KC 32
#define FD 128
#define SLABB 20480  // 20 chunks * 64 lanes * 16 B per component (triangular)

typedef __attribute__((ext_vector_type(8))) short short8;
typedef __attribute__((ext_vector_type(8))) unsigned short ushort8;
typedef __attribute__((ext_vector_type(16))) float f32x16;

#define MFMA(A, B, C) __builtin_amdgcn_mfma_f32_32x32x16_bf16((A), (B), (C), 0, 0, 0)

static __device__ __forceinline__ unsigned short f2bf(float f) {
  unsigned int u = __float_as_uint(f);
  u += 0x7FFFu + ((u >> 16) & 1u);  // RNE
  return (unsigned short)(u >> 16);
}

static __device__ __forceinline__ void gll(const unsigned char* g, unsigned char* l) {
  __builtin_amdgcn_global_load_lds((const __attribute__((address_space(1))) void*)g,
                                   (__attribute__((address_space(3))) void*)l, 16, 0, 0);
}

// --- prep_all: one block per component k (256 threads). ---
// t<128: mp[t] = mu_k @ P_k[:,t]; then v[t] = P_k[t,:] @ mp -> Ximg (scalar
// bf16 store at frag-major position row k, col t); reductions -> ck3.
// Then all 256 threads build the 20-chunk triangular slab of Aimg.
__global__ void prep_all(const float* __restrict__ means, const float* __restrict__ P,
                         const float* __restrict__ w, unsigned char* __restrict__ Aimg,
                         unsigned char* __restrict__ Ximg, float* __restrict__ ck3) {
  const int k = blockIdx.x;   // 0..31
  const int t = threadIdx.x;  // 0..255
  const float* Pk = P + k * FD * FD;
  __shared__ float smp[FD], r1[FD], r2[FD];
  if (t < FD) {
    float acc = 0.f;
    for (int f = 0; f < FD; ++f) acc = fmaf(means[k * FD + f], Pk[f * FD + t], acc);
    smp[t] = acc;
    r1[t] = logf(Pk[t * FD + t]);
    r2[t] = acc * acc;
  }
  __syncthreads();
  if (t < FD) {
    const float* Pr = Pk + t * FD;
    float a2 = 0.f;
    for (int j = 0; j < FD; ++j) a2 = fmaf(Pr[j], smp[j], a2);
    // Ximg frag-major position for (row k, col t):
    // chunk id = (t>>4)*64 + k + 32*((t>>3)&1); byte within chunk = (t&7)*2
    const int id = ((t >> 4) * 64) + k + 32 * ((t >> 3) & 1);
    *(unsigned short*)(Ximg + (size_t)id * 16 + (t & 7) * 2) = f2bf(a2);
  }
  for (int off = 64; off; off >>= 1) {
    if (t < off) { r1[t] += r1[t + off]; r2[t] += r2[t + off]; }
    __syncthreads();
  }
  if (t == 0)
    ck3[k] = logf(w[k]) + r1[0] - 0.5f * ((float)FD * 1.8378770664093453f + r2[0]);
  // triangular A image: 20 chunks c x 64 lanes l = 1280 stores, 5 per thread.
  // c<8: (q=0,s=c); c<10: (q=3,s=c-2); c<16: (q=1,s=c-8); else (q=2,s=c-12).
  for (int i = t; i < 1280; i += 256) {
    const int c = i >> 6, l = i & 63;
    int q, s;
    if (c < 8)       { q = 0; s = c; }
    else if (c < 10) { q = 3; s = c - 2; }
    else if (c < 16) { q = 1; s = c - 8; }
    else             { q = 2; s = c - 12; }
    const int g = q * 32 + (l & 31);
    const int f0 = 16 * s + 8 * (l >> 5);
    ushort8 o;
#pragma unroll
    for (int j = 0; j < 8; ++j) o[j] = f2bf(Pk[(f0 + j) * FD + g]);
    *(ushort8*)(Aimg + (size_t)k * SLABB + (size_t)i * 16) = o;
  }
}

// --- main ---
__global__ __launch_bounds__(256, 2) void gmm_main(const float* __restrict__ x,
                                                   const unsigned char* __restrict__ Aimg,
                                                   const unsigned char* __restrict__ Ximg,
                                                   const float* __restrict__ ck3,
                                                   float* __restrict__ out) {
  __shared__ __align__(16) unsigned char abuf[2 * SLABB];  // 40 KB
  __shared__ __align__(16) float xch[2][4][32];
  __shared__ float ck[KC];
  const int tid = threadIdx.x;
  const int wid = tid >> 6;
  const int lane = tid & 63;
  const int half = lane >> 5;
  const int ln = lane & 31;
  const int p = wid & 1;    // g-tile pair: p=0 -> {0,3}, p=1 -> {1,2}
  const int nq = wid >> 1;  // n-half this wave owns (64 x-rows, tiles t=0,1)
  const int nbase = blockIdx.x * 128;

  if (tid < KC) ck[tid] = ck3[tid];

  // prologue staging: Ximg (8 KB) -> buf1, slab0 -> buf0 (5 gll/wave)
  {
    const unsigned char* gx = Ximg + wid * 2048 + lane * 16;
    unsigned char* lx = abuf + SLABB + wid * 2048;
    gll(gx, lx);
    gll(gx + 1024, lx + 1024);
    const unsigned char* gs = Aimg + wid * 5120 + lane * 16;
    unsigned char* ls = abuf + wid * 5120;
#pragma unroll
    for (int i = 0; i < 5; ++i) gll(gs + i * 1024, ls + i * 1024);
  }

  // B fragments: this wave's 64 x-rows (2 n-tiles), resident all kernel.
  // xf[t][s][j] = x[nbase + nq*64 + t*32 + ln][16s + 8*half + j]  (64 VGPR)
  short8 xf[2][8];
#pragma unroll
  for (int t = 0; t < 2; ++t) {
    const float* xr = x + (size_t)(nbase + nq * 64 + t * 32 + ln) * FD + 8 * half;
#pragma unroll
    for (int s = 0; s < 8; ++s) {
      const float4 a = *(const float4*)(xr + 16 * s);
      const float4 b = *(const float4*)(xr + 16 * s + 4);
      short8 f;
      f[0] = (short)f2bf(a.x); f[1] = (short)f2bf(a.y);
      f[2] = (short)f2bf(a.z); f[3] = (short)f2bf(a.w);
      f[4] = (short)f2bf(b.x); f[5] = (short)f2bf(b.y);
      f[6] = (short)f2bf(b.z); f[7] = (short)f2bf(b.w);
      xf[t][s] = f;
    }
  }

  f32x16 zc;  // persistent zero C-operand
#pragma unroll
  for (int i = 0; i < 16; ++i) zc[i] = 0.f;

  asm volatile("s_waitcnt vmcnt(0)" ::: "memory");
  __syncthreads();

  // xv[n,k] mini-GEMM for the n-tile this wave finalizes (t == p):
  // row k = (i&3)+8*(i>>2)+4*half, col n = nbase + nq*64 + p*32 + ln
  // NOTE: ternary register-select, never xf[p][s] (rule-20).
  f32x16 xv;
  {
    const unsigned char* xb = abuf + SLABB + lane * 16;
    {
      const short8 fx = *(const short8*)xb;
      xv = MFMA(fx, p ? xf[1][0] : xf[0][0], zc);
    }
#pragma unroll
    for (int s = 1; s < 8; ++s) {
      const short8 fx = *(const short8*)(xb + s * 1024);
      xv = MFMA(fx, p ? xf[1][s] : xf[0][s], xv);
    }
  }
  __syncthreads();  // Ximg consumed; buf1 free for slab1 staging

  float m = -__builtin_inff(), ssum = 0.f;

  for (int k = 0; k < KC; ++k) {
    const int RB = (k & 1) * SLABB;
    const int WB = SLABB - RB;
    const int ph = k & 1;
    // this wave's 10 triangular frags (consecutive chunks, conflict-free)
    const unsigned char* rb = abuf + RB + p * 10240 + lane * 16;
    short8 fr[10];
#pragma unroll
    for (int i = 0; i < 10; ++i) fr[i] = *(const short8*)(rb + i * 1024);
    if (k + 1 < KC) {  // stage slab k+1 (5 gll per wave)
      const unsigned char* gs = Aimg + (size_t)(k + 1) * SLABB + wid * 5120 + lane * 16;
      unsigned char* ls = abuf + WB + wid * 5120;
#pragma unroll
      for (int i = 0; i < 5; ++i) gll(gs + i * 1024, ls + i * 1024);
    }
    f32x16 a00, a01, a10, a11;
    __builtin_amdgcn_s_setprio(1);
    if (p == 0) {
      // g-tile 0: full K (s=0..7); g-tile 3: s=6,7
      a00 = MFMA(fr[0], xf[0][0], zc);
      a01 = MFMA(fr[0], xf[1][0], zc);
#pragma unroll
      for (int s = 1; s < 8; ++s) {
        a00 = MFMA(fr[s], xf[0][s], a00);
        a01 = MFMA(fr[s], xf[1][s], a01);
      }
      a10 = MFMA(fr[8], xf[0][6], zc);
      a11 = MFMA(fr[8], xf[1][6], zc);
      a10 = MFMA(fr[9], xf[0][7], a10);
      a11 = MFMA(fr[9], xf[1][7], a11);
    } else {
      // g-tile 1: s=2..7; g-tile 2: s=4..7
      a00 = MFMA(fr[0], xf[0][2], zc);
      a01 = MFMA(fr[0], xf[1][2], zc);
#pragma unroll
      for (int s = 1; s < 6; ++s) {
        a00 = MFMA(fr[s], xf[0][s + 2], a00);
        a01 = MFMA(fr[s], xf[1][s + 2], a01);
      }
      a10 = MFMA(fr[6], xf[0][4], zc);
      a11 = MFMA(fr[6], xf[1][4], zc);
#pragma unroll
      for (int j = 1; j < 4; ++j) {
        a10 = MFMA(fr[6 + j], xf[0][4 + j], a10);
        a11 = MFMA(fr[6 + j], xf[1][4 + j], a11);
      }
    }
    __builtin_amdgcn_s_setprio(0);
    // epilogue: group-1 squares first (issue while group-2 MFMAs drain),
    // then group-2 squares. Scalar fmaf (R18: pk_fma on AGPRs is slower).
    float q0a = 0.f, q1a = 0.f;
#pragma unroll
    for (int i = 0; i < 16; ++i) {
      q0a = fmaf(a00[i], a00[i], q0a);
      q1a = fmaf(a01[i], a01[i], q1a);
    }
    float q0b = 0.f, q1b = 0.f;
#pragma unroll
    for (int i = 0; i < 16; ++i) {
      q0b = fmaf(a10[i], a10[i], q0b);
      q1b = fmaf(a11[i], a11[i], q1b);
    }
    float q0 = q0a + q0b, q1 = q1a + q1b;
    q0 += __shfl_xor(q0, 32, 64);  // both halves hold the 64-g pair partials
    q1 += __shfl_xor(q1, 32, 64);
    float sown = p ? q1 : q0;  // n-tile this wave finalizes (t == p)
    float soth = p ? q0 : q1;  // n-tile the partner (wid^1) finalizes
    if (half == 0) xch[ph][wid ^ 1][ln] = soth;
    if (k + 1 < KC) asm volatile("s_waitcnt vmcnt(0)" ::: "memory");
    __syncthreads();  // xch visibility + staging handoff (one barrier/comp)
    float sfull = sown + xch[ph][wid][ln];  // + partner's 64 g -> full 128-g
    // -2 * x.v_k, made half-uniform with one shfl
    const int owner = (k >> 2) & 1;
    const int idx = (k & 3) | ((k >> 3) << 2);
    float tx = (half == owner) ? xv[idx] : 0.f;
    tx += __shfl_xor(tx, 32, 64);
    sfull = fmaf(-2.f, tx, sfull);
    float vv = ck[k] - 0.5f * sfull;
    float nm = fmaxf(m, vv);
    ssum = ssum * __expf(m - nm) + __expf(vv - nm);
    m = nm;
  }

  if (half == 0) out[nbase + nq * 64 + p * 32 + ln] = m + logf(ssum);
}

extern "C" void kernel_launch(void* const* d_in, const int* in_sizes, int n_in,
                              void* d_out, int out_size, void* d_ws, size_t ws_size,
                              hipStream_t stream) {
  const float* x = (const float*)d_in[0];
  const float* means = (const float*)d_in[1];
  const float* P = (const float*)d_in[2];
  const float* w = (const float*)d_in[3];
  float* out = (float*)d_out;

  unsigned char* ws = (unsigned char*)d_ws;
  unsigned char* Aimg = ws;                      // 32 * 20480 = 655360 B
  unsigned char* Ximg = ws + 655360;             // 8192 B
  float* ck3 = (float*)(ws + 655360 + 8192);     // 128 B

  prep_all<<<32, 256, 0, stream>>>(means, P, w, Aimg, Ximg, ck3);
  gmm_main<<<NPTS / 128, 256, 0, stream>>>(x, Aimg, Ximg, ck3, out);
}

// Round 20
// 59.783 us; speedup vs baseline: 1.1000x; 1.0076x over previous
//
#include <hip/hip_runtime.h>
#include <hip/hip_bf16.h>

// GMM log-likelihood, N=65536, K=32, F=128.
// R19 (triangular compaction + fused prep, main ~51.5 us, serial-pipe-sum
// wall) + two changes:
// 1) ANTI-PHASE: co-resident blocks run identical loops in-phase, so their
//    LDS/MFMA/VALU bursts contend pipe-by-pipe (wall = serial sum of pipes).
//    Blocks with bit-8 set (round-robin dispatch puts b and b+256 on the same
//    CU) sleep ~1800 cyc before the k-loop -> half-comp phase offset -> one
//    block's MFMA burst overlaps the other's LDS/VALU burst.
// 2) xvt wave-private LDS table replaces per-comp owner-select + tx shfl
//    with one broadcast ds_read_b32 (frees 16 AGPRs).

#define NPTS 65536
#define KC 32
#define FD 128
#define SLABB 20480  // 20 chunks * 64 lanes * 16 B per component (triangular)

typedef __attribute__((ext_vector_type(8))) short short8;
typedef __attribute__((ext_vector_type(8))) unsigned short ushort8;
typedef __attribute__((ext_vector_type(16))) float f32x16;

#define MFMA(A, B, C) __builtin_amdgcn_mfma_f32_32x32x16_bf16((A), (B), (C), 0, 0, 0)

static __device__ __forceinline__ unsigned short f2bf(float f) {
  unsigned int u = __float_as_uint(f);
  u += 0x7FFFu + ((u >> 16) & 1u);  // RNE
  return (unsigned short)(u >> 16);
}

static __device__ __forceinline__ void gll(const unsigned char* g, unsigned char* l) {
  __builtin_amdgcn_global_load_lds((const __attribute__((address_space(1))) void*)g,
                                   (__attribute__((address_space(3))) void*)l, 16, 0, 0);
}

// --- prep_all: one block per component k (256 threads). ---
__global__ void prep_all(const float* __restrict__ means, const float* __restrict__ P,
                         const float* __restrict__ w, unsigned char* __restrict__ Aimg,
                         unsigned char* __restrict__ Ximg, float* __restrict__ ck3) {
  const int k = blockIdx.x;   // 0..31
  const int t = threadIdx.x;  // 0..255
  const float* Pk = P + k * FD * FD;
  __shared__ float smp[FD], r1[FD], r2[FD];
  if (t < FD) {
    float acc = 0.f;
    for (int f = 0; f < FD; ++f) acc = fmaf(means[k * FD + f], Pk[f * FD + t], acc);
    smp[t] = acc;
    r1[t] = logf(Pk[t * FD + t]);
    r2[t] = acc * acc;
  }
  __syncthreads();
  if (t < FD) {
    const float* Pr = Pk + t * FD;
    float a2 = 0.f;
    for (int j = 0; j < FD; ++j) a2 = fmaf(Pr[j], smp[j], a2);
    // Ximg frag-major position for (row k, col t):
    const int id = ((t >> 4) * 64) + k + 32 * ((t >> 3) & 1);
    *(unsigned short*)(Ximg + (size_t)id * 16 + (t & 7) * 2) = f2bf(a2);
  }
  for (int off = 64; off; off >>= 1) {
    if (t < off) { r1[t] += r1[t + off]; r2[t] += r2[t + off]; }
    __syncthreads();
  }
  if (t == 0)
    ck3[k] = logf(w[k]) + r1[0] - 0.5f * ((float)FD * 1.8378770664093453f + r2[0]);
  // triangular A image: 20 chunks c x 64 lanes l = 1280 stores, 5 per thread.
  for (int i = t; i < 1280; i += 256) {
    const int c = i >> 6, l = i & 63;
    int q, s;
    if (c < 8)       { q = 0; s = c; }
    else if (c < 10) { q = 3; s = c - 2; }
    else if (c < 16) { q = 1; s = c - 8; }
    else             { q = 2; s = c - 12; }
    const int g = q * 32 + (l & 31);
    const int f0 = 16 * s + 8 * (l >> 5);
    ushort8 o;
#pragma unroll
    for (int j = 0; j < 8; ++j) o[j] = f2bf(Pk[(f0 + j) * FD + g]);
    *(ushort8*)(Aimg + (size_t)k * SLABB + (size_t)i * 16) = o;
  }
}

// --- main ---
__global__ __launch_bounds__(256, 2) void gmm_main(const float* __restrict__ x,
                                                   const unsigned char* __restrict__ Aimg,
                                                   const unsigned char* __restrict__ Ximg,
                                                   const float* __restrict__ ck3,
                                                   float* __restrict__ out) {
  __shared__ __align__(16) unsigned char abuf[2 * SLABB];  // 40 KB
  __shared__ __align__(16) float xvt[4][KC][32];           // 16 KB, wave-private
  __shared__ __align__(16) float xch[2][4][32];
  __shared__ float ck[KC];
  const int tid = threadIdx.x;
  const int wid = tid >> 6;
  const int lane = tid & 63;
  const int half = lane >> 5;
  const int ln = lane & 31;
  const int p = wid & 1;    // g-tile pair: p=0 -> {0,3}, p=1 -> {1,2}
  const int nq = wid >> 1;  // n-half this wave owns (64 x-rows, tiles t=0,1)
  const int nbase = blockIdx.x * 128;

  if (tid < KC) ck[tid] = ck3[tid];

  // prologue staging: Ximg (8 KB) -> buf1, slab0 -> buf0 (5 gll/wave)
  {
    const unsigned char* gx = Ximg + wid * 2048 + lane * 16;
    unsigned char* lx = abuf + SLABB + wid * 2048;
    gll(gx, lx);
    gll(gx + 1024, lx + 1024);
    const unsigned char* gs = Aimg + wid * 5120 + lane * 16;
    unsigned char* ls = abuf + wid * 5120;
#pragma unroll
    for (int i = 0; i < 5; ++i) gll(gs + i * 1024, ls + i * 1024);
  }

  // B fragments: this wave's 64 x-rows (2 n-tiles), resident all kernel.
  short8 xf[2][8];
#pragma unroll
  for (int t = 0; t < 2; ++t) {
    const float* xr = x + (size_t)(nbase + nq * 64 + t * 32 + ln) * FD + 8 * half;
#pragma unroll
    for (int s = 0; s < 8; ++s) {
      const float4 a = *(const float4*)(xr + 16 * s);
      const float4 b = *(const float4*)(xr + 16 * s + 4);
      short8 f;
      f[0] = (short)f2bf(a.x); f[1] = (short)f2bf(a.y);
      f[2] = (short)f2bf(a.z); f[3] = (short)f2bf(a.w);
      f[4] = (short)f2bf(b.x); f[5] = (short)f2bf(b.y);
      f[6] = (short)f2bf(b.z); f[7] = (short)f2bf(b.w);
      xf[t][s] = f;
    }
  }

  f32x16 zc;  // persistent zero C-operand
#pragma unroll
  for (int i = 0; i < 16; ++i) zc[i] = 0.f;

  asm volatile("s_waitcnt vmcnt(0)" ::: "memory");
  __syncthreads();

  // xv[n,k] mini-GEMM for the n-tile this wave finalizes (t == p), dumped to
  // the wave-private xvt LDS table (row k = (i&3)+8*(i>>2)+4*half, col = ln).
  {
    const unsigned char* xb = abuf + SLABB + lane * 16;
    f32x16 xv;
    {
      const short8 fx = *(const short8*)xb;
      xv = MFMA(fx, p ? xf[1][0] : xf[0][0], zc);
    }
#pragma unroll
    for (int s = 1; s < 8; ++s) {
      const short8 fx = *(const short8*)(xb + s * 1024);
      xv = MFMA(fx, p ? xf[1][s] : xf[0][s], xv);
    }
#pragma unroll
    for (int i = 0; i < 16; ++i) {
      const int kk = (i & 3) + 8 * (i >> 2) + 4 * half;
      xvt[wid][kk][ln] = xv[i];
    }
  }
  __syncthreads();  // Ximg consumed; buf1 free for slab1 staging

  // ANTI-PHASE: offset co-resident partner block by ~half a comp period.
  // Round-robin dispatch puts blocks b and b+256 on the same CU -> bit 8.
  if (blockIdx.x & 256) {
    __builtin_amdgcn_s_sleep(7);
    __builtin_amdgcn_s_sleep(7);
    __builtin_amdgcn_s_sleep(7);
    __builtin_amdgcn_s_sleep(7);
  }

  float m = -__builtin_inff(), ssum = 0.f;

  for (int k = 0; k < KC; ++k) {
    const int RB = (k & 1) * SLABB;
    const int WB = SLABB - RB;
    const int ph = k & 1;
    // this wave's 10 triangular frags (consecutive chunks, conflict-free)
    const unsigned char* rb = abuf + RB + p * 10240 + lane * 16;
    short8 fr[10];
#pragma unroll
    for (int i = 0; i < 10; ++i) fr[i] = *(const short8*)(rb + i * 1024);
    if (k + 1 < KC) {  // stage slab k+1 (5 gll per wave)
      const unsigned char* gs = Aimg + (size_t)(k + 1) * SLABB + wid * 5120 + lane * 16;
      unsigned char* ls = abuf + WB + wid * 5120;
#pragma unroll
      for (int i = 0; i < 5; ++i) gll(gs + i * 1024, ls + i * 1024);
    }
    f32x16 a00, a01, a10, a11;
    __builtin_amdgcn_s_setprio(1);
    if (p == 0) {
      // g-tile 0: full K (s=0..7); g-tile 3: s=6,7
      a00 = MFMA(fr[0], xf[0][0], zc);
      a01 = MFMA(fr[0], xf[1][0], zc);
#pragma unroll
      for (int s = 1; s < 8; ++s) {
        a00 = MFMA(fr[s], xf[0][s], a00);
        a01 = MFMA(fr[s], xf[1][s], a01);
      }
      a10 = MFMA(fr[8], xf[0][6], zc);
      a11 = MFMA(fr[8], xf[1][6], zc);
      a10 = MFMA(fr[9], xf[0][7], a10);
      a11 = MFMA(fr[9], xf[1][7], a11);
    } else {
      // g-tile 1: s=2..7; g-tile 2: s=4..7
      a00 = MFMA(fr[0], xf[0][2], zc);
      a01 = MFMA(fr[0], xf[1][2], zc);
#pragma unroll
      for (int s = 1; s < 6; ++s) {
        a00 = MFMA(fr[s], xf[0][s + 2], a00);
        a01 = MFMA(fr[s], xf[1][s + 2], a01);
      }
      a10 = MFMA(fr[6], xf[0][4], zc);
      a11 = MFMA(fr[6], xf[1][4], zc);
#pragma unroll
      for (int j = 1; j < 4; ++j) {
        a10 = MFMA(fr[6 + j], xf[0][4 + j], a10);
        a11 = MFMA(fr[6 + j], xf[1][4 + j], a11);
      }
    }
    __builtin_amdgcn_s_setprio(0);
    // epilogue: group-1 squares first (issue while group-2 MFMAs drain)
    float q0a = 0.f, q1a = 0.f;
#pragma unroll
    for (int i = 0; i < 16; ++i) {
      q0a = fmaf(a00[i], a00[i], q0a);
      q1a = fmaf(a01[i], a01[i], q1a);
    }
    float q0b = 0.f, q1b = 0.f;
#pragma unroll
    for (int i = 0; i < 16; ++i) {
      q0b = fmaf(a10[i], a10[i], q0b);
      q1b = fmaf(a11[i], a11[i], q1b);
    }
    float q0 = q0a + q0b, q1 = q1a + q1b;
    q0 += __shfl_xor(q0, 32, 64);  // both halves hold the 64-g pair partials
    q1 += __shfl_xor(q1, 32, 64);
    float sown = p ? q1 : q0;  // n-tile this wave finalizes (t == p)
    float soth = p ? q0 : q1;  // n-tile the partner (wid^1) finalizes
    if (half == 0) xch[ph][wid ^ 1][ln] = soth;
    if (k + 1 < KC) asm volatile("s_waitcnt vmcnt(0)" ::: "memory");
    __syncthreads();  // xch visibility + staging handoff (one barrier/comp)
    float sfull = sown + xch[ph][wid][ln];  // + partner's 64 g -> full 128-g
    sfull = fmaf(-2.f, xvt[wid][k][ln], sfull);  // v-trick correction
    float vv = ck[k] - 0.5f * sfull;
    float nm = fmaxf(m, vv);
    ssum = ssum * __expf(m - nm) + __expf(vv - nm);
    m = nm;
  }

  if (half == 0) out[nbase + nq * 64 + p * 32 + ln] = m + logf(ssum);
}

extern "C" void kernel_launch(void* const* d_in, const int* in_sizes, int n_in,
                              void* d_out, int out_size, void* d_ws, size_t ws_size,
                              hipStream_t stream) {
  const float* x = (const float*)d_in[0];
  const float* means = (const float*)d_in[1];
  const float* P = (const float*)d_in[2];
  const float* w = (const float*)d_in[3];
  float* out = (float*)d_out;

  unsigned char* ws = (unsigned char*)d_ws;
  unsigned char* Aimg = ws;                      // 32 * 20480 = 655360 B
  unsigned char* Ximg = ws + 655360;             // 8192 B
  float* ck3 = (float*)(ws + 655360 + 8192);     // 128 B

  prep_all<<<32, 256, 0, stream>>>(means, P, w, Aimg, Ximg, ck3);
  gmm_main<<<NPTS / 128, 256, 0, stream>>>(x, Aimg, Ximg, ck3, out);
}

// Round 21
// 58.270 us; speedup vs baseline: 1.1285x; 1.0260x over previous
//
#include <hip/hip_runtime.h>
#include <hip/hip_bf16.h>

// GMM log-likelihood, N=65536, K=32, F=128.
// Main (R20, proven): triangular compaction (s >= 2q -> 20 chunks/comp),
// wave (p,nq) owns 64 g x 64 n, 10 frags -> 20 MFMAs/comp, pairwise xch
// combine, v-trick with wave-private xvt LDS table, 1 barrier/comp,
// anti-phase sleep for co-resident blocks.
// Prep v2: P_k cached in LDS (129-float padded rows, coalesced float4 load);
// all dots / slab build read LDS instead of strided global -- prep was
// ~7-8 us of the 59.8 total, now ~2 us.

#define NPTS 65536
#define KC 32
#define FD 128
#define SLABB 20480  // 20 chunks * 64 lanes * 16 B per component (triangular)

typedef __attribute__((ext_vector_type(8))) short short8;
typedef __attribute__((ext_vector_type(8))) unsigned short ushort8;
typedef __attribute__((ext_vector_type(16))) float f32x16;

#define MFMA(A, B, C) __builtin_amdgcn_mfma_f32_32x32x16_bf16((A), (B), (C), 0, 0, 0)

static __device__ __forceinline__ unsigned short f2bf(float f) {
  unsigned int u = __float_as_uint(f);
  u += 0x7FFFu + ((u >> 16) & 1u);  // RNE
  return (unsigned short)(u >> 16);
}

static __device__ __forceinline__ void gll(const unsigned char* g, unsigned char* l) {
  __builtin_amdgcn_global_load_lds((const __attribute__((address_space(1))) void*)g,
                                   (__attribute__((address_space(3))) void*)l, 16, 0, 0);
}

// --- prep_all v2: one block per component k (256 threads), P_k LDS-cached ---
__global__ __launch_bounds__(256) void prep_all(const float* __restrict__ means,
                                                const float* __restrict__ P,
                                                const float* __restrict__ w,
                                                unsigned char* __restrict__ Aimg,
                                                unsigned char* __restrict__ Ximg,
                                                float* __restrict__ ck3) {
  const int k = blockIdx.x;   // 0..31
  const int t = threadIdx.x;  // 0..255
  const float* Pk = P + k * FD * FD;
  __shared__ float Pl[FD * 129];  // row f at Pl + f*129 (pad kills bank conflicts)
  __shared__ float smp[FD], r1[FD], r2[FD];
  // cooperative coalesced load: 4096 float4s, 16 per thread
  for (int i = t; i < (FD * FD) / 4; i += 256) {
    const float4 v4 = *(const float4*)(Pk + i * 4);
    const int f = (i * 4) >> 7, c = (i * 4) & 127;
    float* d = Pl + f * 129 + c;
    d[0] = v4.x; d[1] = v4.y; d[2] = v4.z; d[3] = v4.w;
  }
  __syncthreads();
  if (t < FD) {
    float acc = 0.f;
    for (int f = 0; f < FD; ++f) acc = fmaf(means[k * FD + f], Pl[f * 129 + t], acc);
    smp[t] = acc;
    r1[t] = logf(Pl[t * 129 + t]);
    r2[t] = acc * acc;
  }
  __syncthreads();
  if (t < FD) {
    float a2 = 0.f;
    for (int j = 0; j < FD; ++j) a2 = fmaf(Pl[t * 129 + j], smp[j], a2);
    // Ximg frag-major position for (row k, col t)
    const int id = ((t >> 4) * 64) + k + 32 * ((t >> 3) & 1);
    *(unsigned short*)(Ximg + (size_t)id * 16 + (t & 7) * 2) = f2bf(a2);
  }
  for (int off = 64; off; off >>= 1) {
    if (t < off) { r1[t] += r1[t + off]; r2[t] += r2[t + off]; }
    __syncthreads();
  }
  if (t == 0)
    ck3[k] = logf(w[k]) + r1[0] - 0.5f * ((float)FD * 1.8378770664093453f + r2[0]);
  // triangular A image: 20 chunks c x 64 lanes l = 1280 stores, 5 per thread.
  for (int i = t; i < 1280; i += 256) {
    const int c = i >> 6, l = i & 63;
    int q, s;
    if (c < 8)       { q = 0; s = c; }
    else if (c < 10) { q = 3; s = c - 2; }
    else if (c < 16) { q = 1; s = c - 8; }
    else             { q = 2; s = c - 12; }
    const int g = q * 32 + (l & 31);
    const int f0 = 16 * s + 8 * (l >> 5);
    ushort8 o;
#pragma unroll
    for (int j = 0; j < 8; ++j) o[j] = f2bf(Pl[(f0 + j) * 129 + g]);
    *(ushort8*)(Aimg + (size_t)k * SLABB + (size_t)i * 16) = o;
  }
}

// --- main (R20, unchanged) ---
__global__ __launch_bounds__(256, 2) void gmm_main(const float* __restrict__ x,
                                                   const unsigned char* __restrict__ Aimg,
                                                   const unsigned char* __restrict__ Ximg,
                                                   const float* __restrict__ ck3,
                                                   float* __restrict__ out) {
  __shared__ __align__(16) unsigned char abuf[2 * SLABB];  // 40 KB
  __shared__ __align__(16) float xvt[4][KC][32];           // 16 KB, wave-private
  __shared__ __align__(16) float xch[2][4][32];
  __shared__ float ck[KC];
  const int tid = threadIdx.x;
  const int wid = tid >> 6;
  const int lane = tid & 63;
  const int half = lane >> 5;
  const int ln = lane & 31;
  const int p = wid & 1;    // g-tile pair: p=0 -> {0,3}, p=1 -> {1,2}
  const int nq = wid >> 1;  // n-half this wave owns (64 x-rows, tiles t=0,1)
  const int nbase = blockIdx.x * 128;

  if (tid < KC) ck[tid] = ck3[tid];

  // prologue staging: Ximg (8 KB) -> buf1, slab0 -> buf0 (5 gll/wave)
  {
    const unsigned char* gx = Ximg + wid * 2048 + lane * 16;
    unsigned char* lx = abuf + SLABB + wid * 2048;
    gll(gx, lx);
    gll(gx + 1024, lx + 1024);
    const unsigned char* gs = Aimg + wid * 5120 + lane * 16;
    unsigned char* ls = abuf + wid * 5120;
#pragma unroll
    for (int i = 0; i < 5; ++i) gll(gs + i * 1024, ls + i * 1024);
  }

  // B fragments: this wave's 64 x-rows (2 n-tiles), resident all kernel.
  short8 xf[2][8];
#pragma unroll
  for (int t = 0; t < 2; ++t) {
    const float* xr = x + (size_t)(nbase + nq * 64 + t * 32 + ln) * FD + 8 * half;
#pragma unroll
    for (int s = 0; s < 8; ++s) {
      const float4 a = *(const float4*)(xr + 16 * s);
      const float4 b = *(const float4*)(xr + 16 * s + 4);
      short8 f;
      f[0] = (short)f2bf(a.x); f[1] = (short)f2bf(a.y);
      f[2] = (short)f2bf(a.z); f[3] = (short)f2bf(a.w);
      f[4] = (short)f2bf(b.x); f[5] = (short)f2bf(b.y);
      f[6] = (short)f2bf(b.z); f[7] = (short)f2bf(b.w);
      xf[t][s] = f;
    }
  }

  f32x16 zc;  // persistent zero C-operand
#pragma unroll
  for (int i = 0; i < 16; ++i) zc[i] = 0.f;

  asm volatile("s_waitcnt vmcnt(0)" ::: "memory");
  __syncthreads();

  // xv mini-GEMM for the n-tile this wave finalizes (t == p) -> xvt table.
  {
    const unsigned char* xb = abuf + SLABB + lane * 16;
    f32x16 xv;
    {
      const short8 fx = *(const short8*)xb;
      xv = MFMA(fx, p ? xf[1][0] : xf[0][0], zc);
    }
#pragma unroll
    for (int s = 1; s < 8; ++s) {
      const short8 fx = *(const short8*)(xb + s * 1024);
      xv = MFMA(fx, p ? xf[1][s] : xf[0][s], xv);
    }
#pragma unroll
    for (int i = 0; i < 16; ++i) {
      const int kk = (i & 3) + 8 * (i >> 2) + 4 * half;
      xvt[wid][kk][ln] = xv[i];
    }
  }
  __syncthreads();  // Ximg consumed; buf1 free for slab1 staging

  // ANTI-PHASE: offset co-resident partner block by ~half a comp period.
  if (blockIdx.x & 256) {
    __builtin_amdgcn_s_sleep(7);
    __builtin_amdgcn_s_sleep(7);
    __builtin_amdgcn_s_sleep(7);
    __builtin_amdgcn_s_sleep(7);
  }

  float m = -__builtin_inff(), ssum = 0.f;

  for (int k = 0; k < KC; ++k) {
    const int RB = (k & 1) * SLABB;
    const int WB = SLABB - RB;
    const int ph = k & 1;
    // this wave's 10 triangular frags (consecutive chunks, conflict-free)
    const unsigned char* rb = abuf + RB + p * 10240 + lane * 16;
    short8 fr[10];
#pragma unroll
    for (int i = 0; i < 10; ++i) fr[i] = *(const short8*)(rb + i * 1024);
    if (k + 1 < KC) {  // stage slab k+1 (5 gll per wave)
      const unsigned char* gs = Aimg + (size_t)(k + 1) * SLABB + wid * 5120 + lane * 16;
      unsigned char* ls = abuf + WB + wid * 5120;
#pragma unroll
      for (int i = 0; i < 5; ++i) gll(gs + i * 1024, ls + i * 1024);
    }
    f32x16 a00, a01, a10, a11;
    __builtin_amdgcn_s_setprio(1);
    if (p == 0) {
      // g-tile 0: full K (s=0..7); g-tile 3: s=6,7
      a00 = MFMA(fr[0], xf[0][0], zc);
      a01 = MFMA(fr[0], xf[1][0], zc);
#pragma unroll
      for (int s = 1; s < 8; ++s) {
        a00 = MFMA(fr[s], xf[0][s], a00);
        a01 = MFMA(fr[s], xf[1][s], a01);
      }
      a10 = MFMA(fr[8], xf[0][6], zc);
      a11 = MFMA(fr[8], xf[1][6], zc);
      a10 = MFMA(fr[9], xf[0][7], a10);
      a11 = MFMA(fr[9], xf[1][7], a11);
    } else {
      // g-tile 1: s=2..7; g-tile 2: s=4..7
      a00 = MFMA(fr[0], xf[0][2], zc);
      a01 = MFMA(fr[0], xf[1][2], zc);
#pragma unroll
      for (int s = 1; s < 6; ++s) {
        a00 = MFMA(fr[s], xf[0][s + 2], a00);
        a01 = MFMA(fr[s], xf[1][s + 2], a01);
      }
      a10 = MFMA(fr[6], xf[0][4], zc);
      a11 = MFMA(fr[6], xf[1][4], zc);
#pragma unroll
      for (int j = 1; j < 4; ++j) {
        a10 = MFMA(fr[6 + j], xf[0][4 + j], a10);
        a11 = MFMA(fr[6 + j], xf[1][4 + j], a11);
      }
    }
    __builtin_amdgcn_s_setprio(0);
    // epilogue: group-1 squares first (issue while group-2 MFMAs drain)
    float q0a = 0.f, q1a = 0.f;
#pragma unroll
    for (int i = 0; i < 16; ++i) {
      q0a = fmaf(a00[i], a00[i], q0a);
      q1a = fmaf(a01[i], a01[i], q1a);
    }
    float q0b = 0.f, q1b = 0.f;
#pragma unroll
    for (int i = 0; i < 16; ++i) {
      q0b = fmaf(a10[i], a10[i], q0b);
      q1b = fmaf(a11[i], a11[i], q1b);
    }
    float q0 = q0a + q0b, q1 = q1a + q1b;
    q0 += __shfl_xor(q0, 32, 64);  // both halves hold the 64-g pair partials
    q1 += __shfl_xor(q1, 32, 64);
    float sown = p ? q1 : q0;  // n-tile this wave finalizes (t == p)
    float soth = p ? q0 : q1;  // n-tile the partner (wid^1) finalizes
    if (half == 0) xch[ph][wid ^ 1][ln] = soth;
    if (k + 1 < KC) asm volatile("s_waitcnt vmcnt(0)" ::: "memory");
    __syncthreads();  // xch visibility + staging handoff (one barrier/comp)
    float sfull = sown + xch[ph][wid][ln];  // + partner's 64 g -> full 128-g
    sfull = fmaf(-2.f, xvt[wid][k][ln], sfull);  // v-trick correction
    float vv = ck[k] - 0.5f * sfull;
    float nm = fmaxf(m, vv);
    ssum = ssum * __expf(m - nm) + __expf(vv - nm);
    m = nm;
  }

  if (half == 0) out[nbase + nq * 64 + p * 32 + ln] = m + logf(ssum);
}

extern "C" void kernel_launch(void* const* d_in, const int* in_sizes, int n_in,
                              void* d_out, int out_size, void* d_ws, size_t ws_size,
                              hipStream_t stream) {
  const float* x = (const float*)d_in[0];
  const float* means = (const float*)d_in[1];
  const float* P = (const float*)d_in[2];
  const float* w = (const float*)d_in[3];
  float* out = (float*)d_out;

  unsigned char* ws = (unsigned char*)d_ws;
  unsigned char* Aimg = ws;                      // 32 * 20480 = 655360 B
  unsigned char* Ximg = ws + 655360;             // 8192 B
  float* ck3 = (float*)(ws + 655360 + 8192);     // 128 B

  prep_all<<<32, 256, 0, stream>>>(means, P, w, Aimg, Ximg, ck3);
  gmm_main<<<NPTS / 128, 256, 0, stream>>>(x, Aimg, Ximg, ck3, out);
}